// Round 1
// baseline (633.581 us; speedup 1.0000x reference)
//
#include <hip/hip_runtime.h>
#include <math.h>

#define F_IN 512
#define H1   16
#define C2   40

// ---------------- zero init (acc buffers + degree) ----------------
__global__ __launch_bounds__(256) void k_zero(int* deg, float* acc1, float* acc2,
                                              int n, int m) {
  int stride = gridDim.x * blockDim.x;
  for (int i = blockIdx.x * blockDim.x + threadIdx.x; i < m; i += stride) {
    if (i < n) deg[i] = 0;
    acc1[i] = 0.f;
    acc2[i] = 0.f;
  }
}

// ---------------- in-degree histogram ----------------
__global__ __launch_bounds__(256) void k_degree(const int* __restrict__ dst, int* deg, int E) {
  int stride = gridDim.x * blockDim.x;
  for (int e = blockIdx.x * blockDim.x + threadIdx.x; e < E; e += stride)
    atomicAdd(&deg[dst[e]], 1);
}

// ---------------- dinv = rsqrt(deg + 1 self-loop) ----------------
__global__ __launch_bounds__(256) void k_dinv(const int* __restrict__ deg, float* dinv, int N) {
  int i = blockIdx.x * blockDim.x + threadIdx.x;
  if (i < N) dinv[i] = rsqrtf((float)(deg[i] + 1));
}

// ---------------- g1 = (x @ W1) * dinv[row] ----------------
// 16 rows per 256-thread block; thread (r,c) computes one output element.
// W1 (512x16 = 32KB) staged in LDS; x row read as float4 (16 lanes broadcast
// the same address -> 4 distinct 16B requests per wave-instr, L1-resident).
__global__ __launch_bounds__(256) void k_gemm1(const float* __restrict__ x,
                                               const float* __restrict__ W1,
                                               const float* __restrict__ dinv,
                                               float* __restrict__ g1, int N) {
  __shared__ float ws[F_IN * H1];
  for (int i = threadIdx.x; i < F_IN * H1; i += 256) ws[i] = W1[i];
  __syncthreads();
  int row = blockIdx.x * 16 + (threadIdx.x >> 4);
  int c = threadIdx.x & 15;
  if (row >= N) return;
  const float4* xr = (const float4*)(x + (size_t)row * F_IN);
  float acc = 0.f;
#pragma unroll 4
  for (int kb = 0; kb < F_IN / 4; kb++) {
    float4 v = xr[kb];
    acc += v.x * ws[(kb * 4 + 0) * H1 + c];
    acc += v.y * ws[(kb * 4 + 1) * H1 + c];
    acc += v.z * ws[(kb * 4 + 2) * H1 + c];
    acc += v.w * ws[(kb * 4 + 3) * H1 + c];
  }
  g1[row * H1 + c] = acc * dinv[row];
}

// ---------------- edge scatter: acc[d] += g[s], 16 features ----------------
// (e,j) decomposition: 16 consecutive lanes handle one edge -> coalesced 64B
// gather of g[s*16..], atomicAdd to 16 consecutive floats at dst.
__global__ __launch_bounds__(256) void k_scatter(const int* __restrict__ src,
                                                 const int* __restrict__ dst,
                                                 const float* __restrict__ g,
                                                 float* acc, long long total) {
  long long stride = (long long)gridDim.x * blockDim.x;
  for (long long t = (long long)blockIdx.x * blockDim.x + threadIdx.x; t < total; t += stride) {
    int e = (int)(t >> 4);
    int j = (int)(t & 15);
    int s = src[e], d = dst[e];
    atomicAdd(&acc[d * H1 + j], g[s * H1 + j]);
  }
}

// ---------------- layer1 finish: a1=relu(dinv*(acc+g1)+b1); g2=a1*dinv ----------------
__global__ __launch_bounds__(256) void k_finish1(const float* __restrict__ acc1,
                                                 const float* __restrict__ g1,
                                                 const float* __restrict__ dinv,
                                                 const float* __restrict__ b1,
                                                 float* __restrict__ g2, int N) {
  int t = blockIdx.x * blockDim.x + threadIdx.x;
  if (t >= N * H1) return;
  int i = t >> 4, j = t & 15;
  float di = dinv[i];
  float v = di * (acc1[t] + g1[t]) + b1[j];
  v = fmaxf(v, 0.f);
  g2[t] = v * di;
}

// ---------------- final: s2 = dinv*(acc2+g2); out = log_softmax(s2@W2 + b2) ----------------
// One wave per node; lane c < 40 computes class logit; full-wave shuffle
// reductions (64-wide) for max and sum.
__global__ __launch_bounds__(256) void k_final(const float* __restrict__ acc2,
                                               const float* __restrict__ g2,
                                               const float* __restrict__ dinv,
                                               const float* __restrict__ W2,
                                               const float* __restrict__ b2,
                                               float* __restrict__ out, int N) {
  int wave = (int)((blockIdx.x * (long long)blockDim.x + threadIdx.x) >> 6);
  int lane = threadIdx.x & 63;
  if (wave >= N) return;
  int d = wave;
  float di = dinv[d];
  float z = -INFINITY;
  if (lane < C2) {
    z = b2[lane];
#pragma unroll
    for (int j = 0; j < H1; j++) {
      float t2 = di * (acc2[d * H1 + j] + g2[d * H1 + j]);
      z += t2 * W2[j * C2 + lane];
    }
  }
  // wave-wide max
  float m = z;
#pragma unroll
  for (int off = 32; off; off >>= 1) m = fmaxf(m, __shfl_xor(m, off, 64));
  float p = (lane < C2) ? expf(z - m) : 0.f;
  float ssum = p;
#pragma unroll
  for (int off = 32; off; off >>= 1) ssum += __shfl_xor(ssum, off, 64);
  if (lane < C2) out[d * C2 + lane] = z - m - logf(ssum);
}

extern "C" void kernel_launch(void* const* d_in, const int* in_sizes, int n_in,
                              void* d_out, int out_size, void* d_ws, size_t ws_size,
                              hipStream_t stream) {
  const float* x  = (const float*)d_in[0];
  const int*   ei = (const int*)d_in[1];
  const float* W1 = (const float*)d_in[2];
  const float* b1 = (const float*)d_in[3];
  const float* W2 = (const float*)d_in[4];
  const float* b2 = (const float*)d_in[5];
  float* out = (float*)d_out;

  int N = in_sizes[0] / F_IN;
  int E = in_sizes[1] / 2;
  const int* src = ei;
  const int* dst = ei + E;

  float* ws   = (float*)d_ws;
  int*   deg  = (int*)ws;                    // N ints
  float* dinv = ws + N;                      // N
  float* g1   = ws + 2 * (size_t)N;          // N*16
  float* g2   = g1 + (size_t)N * H1;         // N*16
  float* acc1 = g2 + (size_t)N * H1;         // N*16
  float* acc2 = acc1 + (size_t)N * H1;       // N*16

  k_zero<<<1024, 256, 0, stream>>>(deg, acc1, acc2, N, N * H1);
  k_degree<<<4096, 256, 0, stream>>>(dst, deg, E);
  k_dinv<<<(N + 255) / 256, 256, 0, stream>>>(deg, dinv, N);
  k_gemm1<<<(N + 15) / 16, 256, 0, stream>>>(x, W1, dinv, g1, N);
  k_scatter<<<8192, 256, 0, stream>>>(src, dst, g1, acc1, (long long)E * H1);
  k_finish1<<<(N * H1 + 255) / 256, 256, 0, stream>>>(acc1, g1, dinv, b1, g2, N);
  k_scatter<<<8192, 256, 0, stream>>>(src, dst, g2, acc2, (long long)E * H1);
  k_final<<<(N + 3) / 4, 256, 0, stream>>>(acc2, g2, dinv, W2, b2, out, N);
}